// Round 1
// baseline (367.068 us; speedup 1.0000x reference)
//
#include <hip/hip_runtime.h>

// Problem constants
constexpr int B  = 64;
constexpr int U  = 512;
constexpr int AE = 1024;
constexpr int UE = 256;
constexpr int A  = 256;     // head size
constexpr int KQ = AE + UE; // 1280

typedef _Float16 f16x8 __attribute__((ext_vector_type(8)));
typedef _Float16 f16x4 __attribute__((ext_vector_type(4)));
typedef float    f32x4 __attribute__((ext_vector_type(4)));

// ---------------------------------------------------------------------------
// K0: cast+transpose weights to fp16 [N][K] so GEMM B-frags are k-contiguous
// ---------------------------------------------------------------------------
__global__ void prep(const float* __restrict__ Wq, const float* __restrict__ Wk,
                     _Float16* __restrict__ WqT, _Float16* __restrict__ WkT) {
    int idx = blockIdx.x * 256 + threadIdx.x;
    if (idx < KQ * A) {
        int k = idx >> 8, n = idx & 255;
        WqT[(size_t)n * KQ + k] = (_Float16)Wq[idx];
    } else {
        int j = idx - KQ * A;
        if (j < A * A) {
            int k = j >> 8, n = j & 255;
            WkT[(size_t)n * A + k] = (_Float16)Wk[j];
        }
    }
}

// ---------------------------------------------------------------------------
// K1/K2: C[m][n] = (concat A1|A2)[m][k] * BT[n][k] + bias[n], fp16 out in
// permuted layout [b=row>>9][c=col>>5][u=row&511][col&31] for attn streaming.
//
// R1 change: BM 64->32 so grid doubles to 1024 blocks -> 4 blocks/CU (was
// grid-limited to 2/CU, OccupancyPercent 36.5, all pipes <16% busy =>
// latency-bound). Wave tile 32x32 (2x2 of 16x16), acc 16 regs;
// __launch_bounds__(512,8) pins VGPR<=64 so occupancy is thread-limited
// (4 blocks/CU = 100%). LDS 36 KB (fits 4/CU). Pipeline structure kept:
// 1-deep register prefetch, 2 barriers/iter, 16B-chunk XOR bank swizzle.
// ---------------------------------------------------------------------------
__global__ __launch_bounds__(512, 8) void gemm(
    const float* __restrict__ A1, int s1, int split,
    const float* __restrict__ A2, int s2,
    const _Float16* __restrict__ BT,   // [256][Ktot] fp16
    const float* __restrict__ bias,    // [256]
    _Float16* __restrict__ Out,        // permuted, see above
    int Ktot)
{
    __shared__ __align__(16) _Float16 Al[2][32][32];   // 4 KB  (2 k-planes of 32)
    __shared__ __align__(16) _Float16 Bl[2][256][32];  // 32 KB

    const int t    = threadIdx.x;
    const int lane = t & 63;
    const int w    = t >> 6;              // 0..7
    const int mbase = blockIdx.x * 32;

    const int wn = w * 32;                // wave col base, rows shared by all waves

    f32x4 acc[2][2] = {};

    // A staging mapping: thread -> (row ar, 4-float k-chunk aq)
    const int ar  = t >> 4;               // 0..31
    const int aq  = t & 15;               // 0..15 (4 floats each)
    const int ap  = aq >> 3;              // plane
    const int ah  = (aq & 7) * 4;         // half offset within plane (0..28)
    const int asw = ((ah >> 3) ^ ((ar >> 1) & 3)) * 8 + (ah & 7); // swizzled
    const size_t grow = mbase + ar;

    // B staging mapping: thread -> (row t>>1, plane t&1), 4 16B chunks j
    const int brow = t >> 1;              // 0..255
    const int bpl  = t & 1;               // k-plane
    const int bsw  = (brow >> 1) & 3;     // swizzle component

    float4 areg;
    f16x8 breg[4];

    auto loadA = [&](int k0) {
        int kg = k0 + aq * 4;
        const float* src = (kg < split) ? (A1 + grow * (size_t)s1 + kg)
                                        : (A2 + grow * (size_t)s2 + (kg - split));
        areg = *(const float4*)src;
    };
    auto loadB = [&](int k0) {
        const _Float16* src = BT + (size_t)brow * Ktot + k0 + bpl * 32;
        #pragma unroll
        for (int j = 0; j < 4; j++)
            breg[j] = *(const f16x8*)(src + j * 8);
    };

    loadA(0);
    loadB(0);

    const int rp = ((lane >> 4) ^ ((lane >> 1) & 3)) * 8;  // swizzled read chunk
    const int nk = Ktot >> 6;
    for (int kb = 0; kb < nk; kb++) {
        __syncthreads();   // prev iter's LDS readers done
        {   // ds_write staged regs (compiler inserts vmcnt wait here)
            f16x4 hv;
            hv[0] = (_Float16)areg.x; hv[1] = (_Float16)areg.y;
            hv[2] = (_Float16)areg.z; hv[3] = (_Float16)areg.w;
            *(f16x4*)(&Al[ap][ar][asw]) = hv;
            #pragma unroll
            for (int j = 0; j < 4; j++)
                *(f16x8*)(&Bl[bpl][brow][(j ^ bsw) * 8]) = breg[j];
        }
        __syncthreads();
        if (kb + 1 < nk) { loadA(kb * 64 + 64); loadB(kb * 64 + 64); }
        #pragma unroll
        for (int p = 0; p < 2; p++) {
            f16x8 af[2], bf[2];
            #pragma unroll
            for (int mt = 0; mt < 2; mt++)
                af[mt] = *(const f16x8*)(&Al[p][mt * 16 + (lane & 15)][rp]);
            #pragma unroll
            for (int nt = 0; nt < 2; nt++)
                bf[nt] = *(const f16x8*)(&Bl[p][wn + nt * 16 + (lane & 15)][rp]);
            #pragma unroll
            for (int mt = 0; mt < 2; mt++)
                #pragma unroll
                for (int nt = 0; nt < 2; nt++)
                    acc[mt][nt] = __builtin_amdgcn_mfma_f32_16x16x32_f16(
                        af[mt], bf[nt], acc[mt][nt], 0, 0, 0);
        }
    }
    // epilogue: C layout col=lane&15, row=(lane>>4)*4+reg; permuted store
    const int col0 = wn + (lane & 15);
    const int rsub = (lane >> 4) * 4;
    #pragma unroll
    for (int nt = 0; nt < 2; nt++) {
        const int col = col0 + nt * 16;
        const float bv = bias[col];
        const int c5 = col >> 5, c31 = col & 31;
        #pragma unroll
        for (int mt = 0; mt < 2; mt++)
            #pragma unroll
            for (int r = 0; r < 4; r++) {
                int row = mbase + mt * 16 + rsub + r;
                int bb = row >> 9, u = row & 511;
                Out[(((size_t)bb * 8 + c5) * 512 + u) * 32 + c31] =
                    (_Float16)(acc[mt][nt][r] + bv);
            }
    }
}

// ---------------------------------------------------------------------------
// K3: block = (batch, 64 q-rows), 512 thr / 8 waves. S = Qh Kh^T / 16 with
// multiplicative mask, row softmax entirely in registers + tiny LDS combine.
// K streamed in 8 chunks of 32 d via register-prefetch pipeline.
// ---------------------------------------------------------------------------
__global__ __launch_bounds__(512) void attn(
    const _Float16* __restrict__ Qh, const _Float16* __restrict__ Kh,
    const int* __restrict__ nr_own_units, const int* __restrict__ nr_units_enemy,
    const int* __restrict__ nr_own_flags, float* __restrict__ Out)
{
    __shared__ __align__(16) _Float16 Ql[8][64][32];   // 32 KB, 8 d-chunks
    __shared__ __align__(16) _Float16 Kl[512][32];     // 32 KB, one d-chunk
    __shared__ float red[64][4];                       // per-row cross-wave scratch

    const int t    = threadIdx.x;
    const int lane = t & 63;
    const int w    = t >> 6;                 // 0..7
    const int b    = blockIdx.y;
    const int qbase = blockIdx.x * 64;

    const int nf = nr_own_flags[b];
    const int nu = nr_own_units[b];
    const int ne = nr_units_enemy[b];

    const int wm = (w & 1) * 32;             // wave row base (0/32)
    const int wn = (w >> 1) * 128;           // wave col base (0..384)

    // ---- stage Q (once): regs -> LDS, swizzled
    f16x8 qreg[4];
    {
        const _Float16* Qb = Qh + ((size_t)b * 8 * 512 + qbase) * 32;
        #pragma unroll
        for (int j = 0; j < 4; j++) {
            int s = j * 512 + t;
            int p = s >> 8, row = (s & 255) >> 2, cq = s & 3;
            qreg[j] = *(const f16x8*)(Qb + ((size_t)p * 512 + row) * 32 + cq * 8);
        }
        #pragma unroll
        for (int j = 0; j < 4; j++) {
            int s = j * 512 + t;
            int p = s >> 8, row = (s & 255) >> 2, cq = s & 3;
            *(f16x8*)(&Ql[p][row][(cq ^ ((row >> 1) & 3)) * 8]) = qreg[j];
        }
    }

    // ---- K chunk staging mapping: s = j*512 + t -> row = s>>2, cq = s&3
    const _Float16* Kb = Kh + (size_t)b * 8 * 512 * 32;
    f16x8 kreg[4];
    const int krow = t >> 2;                 // + j*128
    const int kq   = t & 3;
    auto loadK = [&](int c) {
        const _Float16* Kc = Kb + (size_t)c * 512 * 32;
        #pragma unroll
        for (int j = 0; j < 4; j++)
            kreg[j] = *(const f16x8*)(Kc + ((size_t)(j * 128 + krow)) * 32 + kq * 8);
    };
    loadK(0);

    f32x4 acc[2][8] = {};
    const int rsw = (((lane & 15) >> 1) & 3);
    for (int c = 0; c < 8; c++) {
        __syncthreads();   // c==0: publish Ql; else: prev Kl readers done
        #pragma unroll
        for (int j = 0; j < 4; j++) {
            int row = j * 128 + krow;
            *(f16x8*)(&Kl[row][(kq ^ ((row >> 1) & 3)) * 8]) = kreg[j];
        }
        __syncthreads();
        if (c < 7) loadK(c + 1);
        f16x8 af[2], bf[8];
        #pragma unroll
        for (int mt = 0; mt < 2; mt++)
            af[mt] = *(const f16x8*)(&Ql[c][wm + mt * 16 + (lane & 15)][((lane >> 4) ^ rsw) * 8]);
        #pragma unroll
        for (int nt = 0; nt < 8; nt++)
            bf[nt] = *(const f16x8*)(&Kl[wn + nt * 16 + (lane & 15)][((lane >> 4) ^ rsw) * 8]);
        #pragma unroll
        for (int mt = 0; mt < 2; mt++)
            #pragma unroll
            for (int nt = 0; nt < 8; nt++)
                acc[mt][nt] = __builtin_amdgcn_mfma_f32_16x16x32_f16(
                    af[mt], bf[nt], acc[mt][nt], 0, 0, 0);
    }

    // ---- mask + scale in registers
    const int rsub = (lane >> 4) * 4;
    #pragma unroll
    for (int mt = 0; mt < 2; mt++)
        #pragma unroll
        for (int nt = 0; nt < 8; nt++)
            #pragma unroll
            for (int r = 0; r < 4; r++) {
                int rl = wm + mt * 16 + rsub + r;
                int uq = qbase + rl;
                int col = wn + nt * 16 + (lane & 15);
                bool ok = (col < ne) && (uq >= nf) && (uq < nu);
                acc[mt][nt][r] = acc[mt][nt][r] * 0.0625f * (ok ? 1.0f : 1e-9f);
            }

    // ---- row max: over nt in-lane, then across 16-lane group, then cross-wave
    float mx[2][4];
    #pragma unroll
    for (int mt = 0; mt < 2; mt++)
        #pragma unroll
        for (int r = 0; r < 4; r++) {
            float m = acc[mt][0][r];
            #pragma unroll
            for (int nt = 1; nt < 8; nt++) m = fmaxf(m, acc[mt][nt][r]);
            #pragma unroll
            for (int off = 1; off <= 8; off <<= 1) m = fmaxf(m, __shfl_xor(m, off));
            mx[mt][r] = m;
        }
    if ((lane & 15) == 0) {
        #pragma unroll
        for (int mt = 0; mt < 2; mt++)
            #pragma unroll
            for (int r = 0; r < 4; r++)
                red[wm + mt * 16 + rsub + r][w >> 1] = mx[mt][r];
    }
    __syncthreads();
    #pragma unroll
    for (int mt = 0; mt < 2; mt++)
        #pragma unroll
        for (int r = 0; r < 4; r++) {
            f32x4 v = *(const f32x4*)(&red[wm + mt * 16 + rsub + r][0]);
            mx[mt][r] = fmaxf(fmaxf(v[0], v[1]), fmaxf(v[2], v[3]));
        }
    __syncthreads();   // everyone read max before red is reused for sums

    // ---- exp + row sum
    float sm[2][4];
    #pragma unroll
    for (int mt = 0; mt < 2; mt++)
        #pragma unroll
        for (int r = 0; r < 4; r++) {
            float s = 0.f;
            #pragma unroll
            for (int nt = 0; nt < 8; nt++) {
                float e = __expf(acc[mt][nt][r] - mx[mt][r]);
                acc[mt][nt][r] = e;
                s += e;
            }
            #pragma unroll
            for (int off = 1; off <= 8; off <<= 1) s += __shfl_xor(s, off);
            sm[mt][r] = s;
        }
    if ((lane & 15) == 0) {
        #pragma unroll
        for (int mt = 0; mt < 2; mt++)
            #pragma unroll
            for (int r = 0; r < 4; r++)
                red[wm + mt * 16 + rsub + r][w >> 1] = sm[mt][r];
    }
    __syncthreads();

    // ---- normalize + store
    #pragma unroll
    for (int mt = 0; mt < 2; mt++)
        #pragma unroll
        for (int r = 0; r < 4; r++) {
            int rl = wm + mt * 16 + rsub + r;
            f32x4 v = *(const f32x4*)(&red[rl][0]);
            float inv = 1.0f / (v[0] + v[1] + v[2] + v[3]);
            float* orow = Out + ((size_t)b * 512 + qbase + rl) * 512 + wn + (lane & 15);
            #pragma unroll
            for (int nt = 0; nt < 8; nt++)
                orow[nt * 16] = acc[mt][nt][r] * inv;
        }
}

// ---------------------------------------------------------------------------
extern "C" void kernel_launch(void* const* d_in, const int* in_sizes, int n_in,
                              void* d_out, int out_size, void* d_ws, size_t ws_size,
                              hipStream_t stream) {
    const float* ar    = (const float*)d_in[0];   // [B,U,AE]
    const float* own   = (const float*)d_in[1];   // [B,U,UE]
    const float* enemy = (const float*)d_in[2];   // [B,U,UE]
    const int*   n_own   = (const int*)d_in[3];   // nr_own_units
    const int*   n_enemy = (const int*)d_in[4];   // nr_units_enemy
    const int*   n_flags = (const int*)d_in[5];   // nr_own_flags
    const float* Wq = (const float*)d_in[6];
    const float* bq = (const float*)d_in[7];
    const float* Wk = (const float*)d_in[8];
    const float* bk = (const float*)d_in[9];
    float* out = (float*)d_out;

    char* ws = (char*)d_ws;
    _Float16* WqT = (_Float16*)(ws);                       // 256x1280 = 655360 B
    _Float16* WkT = (_Float16*)(ws + 655360);              // 256x256  = 131072 B
    _Float16* Qh  = (_Float16*)(ws + 786432);              // [64][8][512][32] f16
    _Float16* Kh  = (_Float16*)(ws + 786432 + 16777216);   // [64][8][512][32] f16

    prep<<<dim3((KQ * A + A * A) / 256), dim3(256), 0, stream>>>(Wq, Wk, WqT, WkT);

    // Q = concat(ar, own) @ Wq + bq   (grid 1024: BM=32 -> 4 blocks/CU)
    gemm<<<dim3(1024), dim3(512), 0, stream>>>(ar, AE, AE, own, UE, WqT, bq, Qh, KQ);
    // K = enemy @ Wk + bk  (split=0 -> always A2 path)
    gemm<<<dim3(1024), dim3(512), 0, stream>>>(enemy, UE, 0, enemy, UE, WkT, bk, Kh, A);

    attn<<<dim3(8, B), dim3(512), 0, stream>>>(Qh, Kh, n_own, n_enemy, n_flags, out);
}

// Round 2
// 332.330 us; speedup vs baseline: 1.1045x; 1.1045x over previous
//
#include <hip/hip_runtime.h>

// Problem constants
constexpr int B  = 64;
constexpr int U  = 512;
constexpr int AE = 1024;
constexpr int UE = 256;
constexpr int A  = 256;     // head size
constexpr int KQ = AE + UE; // 1280

typedef _Float16 f16x8 __attribute__((ext_vector_type(8)));
typedef float    f32x4 __attribute__((ext_vector_type(4)));

// ---------------------------------------------------------------------------
// K0: cast+transpose weights to fp16 [N][K] so GEMM B-frags are k-contiguous
// ---------------------------------------------------------------------------
__global__ void prep(const float* __restrict__ Wq, const float* __restrict__ Wk,
                     _Float16* __restrict__ WqT, _Float16* __restrict__ WkT) {
    int idx = blockIdx.x * 256 + threadIdx.x;
    if (idx < KQ * A) {
        int k = idx >> 8, n = idx & 255;
        WqT[(size_t)n * KQ + k] = (_Float16)Wq[idx];
    } else {
        int j = idx - KQ * A;
        if (j < A * A) {
            int k = j >> 8, n = j & 255;
            WkT[(size_t)n * A + k] = (_Float16)Wk[j];
        }
    }
}

// ---------------------------------------------------------------------------
// K1/K2: C[m][n] = (concat A1|A2)[m][k] * BT[n][k] + bias[n], fp16 out in
// permuted layout [b=row>>9][c=col>>5][u=row&511][col&31] for attn streaming.
//
// R2: back to BM=64/BN=256 (R0 geometry + swizzles verbatim; R1's BM=32
// raised occupancy but regressed — bottleneck is phase serialization, not
// TLP). Structural change: DOUBLE-BUFFERED LDS + ONE raw s_barrier/iter with
// lgkmcnt(0) only — global loads for t+1 stay in flight across the barrier
// (they target private regs; no cross-wave VMEM hazard), covered by the
// whole MFMA phase. ds_write moved after MFMA (sched_barrier pins it late).
// LDS 80 KB -> 2 blocks/CU (same residency as R0).
// ---------------------------------------------------------------------------
__global__ __launch_bounds__(512) void gemm(
    const float* __restrict__ A1, int s1, int split,
    const float* __restrict__ A2, int s2,
    const _Float16* __restrict__ BT,   // [256][Ktot] fp16
    const float* __restrict__ bias,    // [256]
    _Float16* __restrict__ Out,        // permuted, see above
    int Ktot)
{
    __shared__ __align__(16) _Float16 Al[2][2][64][32];   // [buf][plane][row][32] 16 KB
    __shared__ __align__(16) _Float16 Bl[2][2][256][32];  // [buf][plane][row][32] 64 KB

    const int t    = threadIdx.x;
    const int lane = t & 63;
    const int w    = t >> 6;              // 0..7
    const int mbase = blockIdx.x * 64;

    const int wm = (w & 1) * 32;          // wave row base
    const int wn = (w >> 1) * 64;         // wave col base

    f32x4 acc[2][4] = {};

    // A staging mapping: thread -> (row ar, 8-elem k-chunk aq)  [R0 verbatim]
    const int ar  = t >> 3;               // 0..63
    const int aq  = t & 7;                // 0..7
    const int ap  = aq >> 2;              // plane
    const int asw = ((aq & 3) ^ ((ar >> 1) & 3)) * 8;  // swizzled chunk offset
    const size_t grow = mbase + ar;

    // B staging mapping: s = j*512 + t  [R0 verbatim]
    int bp[4], bn[4], bq[4], bsw[4];
    #pragma unroll
    for (int j = 0; j < 4; j++) {
        int s = j * 512 + t;
        bp[j] = s >> 10;
        bn[j] = (s & 1023) >> 2;
        bq[j] = s & 3;
        bsw[j] = ((bq[j] ^ ((bn[j] >> 1) & 3))) * 8;
    }

    float4 areg0, areg1;
    f16x8 breg[4];

    auto loadA = [&](int k0) {
        int kg = k0 + aq * 8;
        const float* src = (kg < split) ? (A1 + grow * (size_t)s1 + kg)
                                        : (A2 + grow * (size_t)s2 + (kg - split));
        areg0 = ((const float4*)src)[0];
        areg1 = ((const float4*)src)[1];
    };
    auto loadB = [&](int k0) {
        #pragma unroll
        for (int j = 0; j < 4; j++)
            breg[j] = *(const f16x8*)(BT + (size_t)bn[j] * Ktot + k0 + bp[j] * 32 + bq[j] * 8);
    };
    auto writeAB = [&](int nb) {
        f16x8 hv;
        hv[0] = (_Float16)areg0.x; hv[1] = (_Float16)areg0.y;
        hv[2] = (_Float16)areg0.z; hv[3] = (_Float16)areg0.w;
        hv[4] = (_Float16)areg1.x; hv[5] = (_Float16)areg1.y;
        hv[6] = (_Float16)areg1.z; hv[7] = (_Float16)areg1.w;
        *(f16x8*)(&Al[nb][ap][ar][asw]) = hv;
        #pragma unroll
        for (int j = 0; j < 4; j++)
            *(f16x8*)(&Bl[nb][bp[j]][bn[j]][bsw[j]]) = breg[j];
    };

    // prologue: stage tile 0 into buf 0 (one cold stall, unavoidable)
    loadA(0);
    loadB(0);
    writeAB(0);
    asm volatile("s_waitcnt lgkmcnt(0)" ::: "memory");
    __builtin_amdgcn_s_barrier();
    __builtin_amdgcn_sched_barrier(0);

    const int rsw = (((lane & 15) >> 1) & 3);  // read-side swizzle component
    const int nk = Ktot >> 6;
    int cur = 0;
    for (int kb = 0; kb < nk; kb++) {
        const bool more = (kb + 1 < nk);
        if (more) { loadA(kb * 64 + 64); loadB(kb * 64 + 64); }  // in flight across MFMA phase
        #pragma unroll
        for (int p = 0; p < 2; p++) {
            f16x8 af[2], bf[4];
            #pragma unroll
            for (int mt = 0; mt < 2; mt++)
                af[mt] = *(const f16x8*)(&Al[cur][p][wm + mt * 16 + (lane & 15)][(((lane >> 4) ^ rsw)) * 8]);
            #pragma unroll
            for (int nt = 0; nt < 4; nt++)
                bf[nt] = *(const f16x8*)(&Bl[cur][p][wn + nt * 16 + (lane & 15)][(((lane >> 4) ^ rsw)) * 8]);
            #pragma unroll
            for (int mt = 0; mt < 2; mt++)
                #pragma unroll
                for (int nt = 0; nt < 4; nt++)
                    acc[mt][nt] = __builtin_amdgcn_mfma_f32_16x16x32_f16(
                        af[mt], bf[nt], acc[mt][nt], 0, 0, 0);
        }
        __builtin_amdgcn_sched_barrier(0);   // pin the next-buf write AFTER the MFMA phase
        if (more) writeAB(cur ^ 1);          // vmcnt wait lands here, after compute
        asm volatile("s_waitcnt lgkmcnt(0)" ::: "memory");
        __builtin_amdgcn_s_barrier();        // raw barrier: no vmcnt drain
        __builtin_amdgcn_sched_barrier(0);
        cur ^= 1;
    }

    // epilogue: C layout col=lane&15, row=(lane>>4)*4+reg; permuted store
    const int col0 = wn + (lane & 15);
    const int rsub = (lane >> 4) * 4;
    #pragma unroll
    for (int nt = 0; nt < 4; nt++) {
        const int col = col0 + nt * 16;
        const float bv = bias[col];
        const int c5 = col >> 5, c31 = col & 31;
        #pragma unroll
        for (int mt = 0; mt < 2; mt++)
            #pragma unroll
            for (int r = 0; r < 4; r++) {
                int row = mbase + wm + mt * 16 + rsub + r;
                int bb = row >> 9, u = row & 511;
                Out[(((size_t)bb * 8 + c5) * 512 + u) * 32 + c31] =
                    (_Float16)(acc[mt][nt][r] + bv);
            }
    }
}

// ---------------------------------------------------------------------------
// K3: block = (batch, 64 q-rows), 512 thr / 8 waves. S = Qh Kh^T / 16 with
// multiplicative mask, row softmax entirely in registers + tiny LDS combine.
// K streamed in 8 chunks of 32 d via register-prefetch pipeline.
// (unchanged this round — clean attribution of the gemm restructure)
// ---------------------------------------------------------------------------
__global__ __launch_bounds__(512) void attn(
    const _Float16* __restrict__ Qh, const _Float16* __restrict__ Kh,
    const int* __restrict__ nr_own_units, const int* __restrict__ nr_units_enemy,
    const int* __restrict__ nr_own_flags, float* __restrict__ Out)
{
    __shared__ __align__(16) _Float16 Ql[8][64][32];   // 32 KB, 8 d-chunks
    __shared__ __align__(16) _Float16 Kl[512][32];     // 32 KB, one d-chunk
    __shared__ float red[64][4];                       // per-row cross-wave scratch

    const int t    = threadIdx.x;
    const int lane = t & 63;
    const int w    = t >> 6;                 // 0..7
    const int b    = blockIdx.y;
    const int qbase = blockIdx.x * 64;

    const int nf = nr_own_flags[b];
    const int nu = nr_own_units[b];
    const int ne = nr_units_enemy[b];

    const int wm = (w & 1) * 32;             // wave row base (0/32)
    const int wn = (w >> 1) * 128;           // wave col base (0..384)

    // ---- stage Q (once): regs -> LDS, swizzled
    f16x8 qreg[4];
    {
        const _Float16* Qb = Qh + ((size_t)b * 8 * 512 + qbase) * 32;
        #pragma unroll
        for (int j = 0; j < 4; j++) {
            int s = j * 512 + t;
            int p = s >> 8, row = (s & 255) >> 2, cq = s & 3;
            qreg[j] = *(const f16x8*)(Qb + ((size_t)p * 512 + row) * 32 + cq * 8);
        }
        #pragma unroll
        for (int j = 0; j < 4; j++) {
            int s = j * 512 + t;
            int p = s >> 8, row = (s & 255) >> 2, cq = s & 3;
            *(f16x8*)(&Ql[p][row][(cq ^ ((row >> 1) & 3)) * 8]) = qreg[j];
        }
    }

    // ---- K chunk staging mapping: s = j*512 + t -> row = s>>2, cq = s&3
    const _Float16* Kb = Kh + (size_t)b * 8 * 512 * 32;
    f16x8 kreg[4];
    const int krow = t >> 2;                 // + j*128
    const int kq   = t & 3;
    auto loadK = [&](int c) {
        const _Float16* Kc = Kb + (size_t)c * 512 * 32;
        #pragma unroll
        for (int j = 0; j < 4; j++)
            kreg[j] = *(const f16x8*)(Kc + ((size_t)(j * 128 + krow)) * 32 + kq * 8);
    };
    loadK(0);

    f32x4 acc[2][8] = {};
    const int rsw = (((lane & 15) >> 1) & 3);
    for (int c = 0; c < 8; c++) {
        __syncthreads();   // c==0: publish Ql; else: prev Kl readers done
        #pragma unroll
        for (int j = 0; j < 4; j++) {
            int row = j * 128 + krow;
            *(f16x8*)(&Kl[row][(kq ^ ((row >> 1) & 3)) * 8]) = kreg[j];
        }
        __syncthreads();
        if (c < 7) loadK(c + 1);
        f16x8 af[2], bf[8];
        #pragma unroll
        for (int mt = 0; mt < 2; mt++)
            af[mt] = *(const f16x8*)(&Ql[c][wm + mt * 16 + (lane & 15)][((lane >> 4) ^ rsw) * 8]);
        #pragma unroll
        for (int nt = 0; nt < 8; nt++)
            bf[nt] = *(const f16x8*)(&Kl[wn + nt * 16 + (lane & 15)][((lane >> 4) ^ rsw) * 8]);
        #pragma unroll
        for (int mt = 0; mt < 2; mt++)
            #pragma unroll
            for (int nt = 0; nt < 8; nt++)
                acc[mt][nt] = __builtin_amdgcn_mfma_f32_16x16x32_f16(
                    af[mt], bf[nt], acc[mt][nt], 0, 0, 0);
    }

    // ---- mask + scale in registers
    const int rsub = (lane >> 4) * 4;
    #pragma unroll
    for (int mt = 0; mt < 2; mt++)
        #pragma unroll
        for (int nt = 0; nt < 8; nt++)
            #pragma unroll
            for (int r = 0; r < 4; r++) {
                int rl = wm + mt * 16 + rsub + r;
                int uq = qbase + rl;
                int col = wn + nt * 16 + (lane & 15);
                bool ok = (col < ne) && (uq >= nf) && (uq < nu);
                acc[mt][nt][r] = acc[mt][nt][r] * 0.0625f * (ok ? 1.0f : 1e-9f);
            }

    // ---- row max: over nt in-lane, then across 16-lane group, then cross-wave
    float mx[2][4];
    #pragma unroll
    for (int mt = 0; mt < 2; mt++)
        #pragma unroll
        for (int r = 0; r < 4; r++) {
            float m = acc[mt][0][r];
            #pragma unroll
            for (int nt = 1; nt < 8; nt++) m = fmaxf(m, acc[mt][nt][r]);
            #pragma unroll
            for (int off = 1; off <= 8; off <<= 1) m = fmaxf(m, __shfl_xor(m, off));
            mx[mt][r] = m;
        }
    if ((lane & 15) == 0) {
        #pragma unroll
        for (int mt = 0; mt < 2; mt++)
            #pragma unroll
            for (int r = 0; r < 4; r++)
                red[wm + mt * 16 + rsub + r][w >> 1] = mx[mt][r];
    }
    __syncthreads();
    #pragma unroll
    for (int mt = 0; mt < 2; mt++)
        #pragma unroll
        for (int r = 0; r < 4; r++) {
            f32x4 v = *(const f32x4*)(&red[wm + mt * 16 + rsub + r][0]);
            mx[mt][r] = fmaxf(fmaxf(v[0], v[1]), fmaxf(v[2], v[3]));
        }
    __syncthreads();   // everyone read max before red is reused for sums

    // ---- exp + row sum
    float sm[2][4];
    #pragma unroll
    for (int mt = 0; mt < 2; mt++)
        #pragma unroll
        for (int r = 0; r < 4; r++) {
            float s = 0.f;
            #pragma unroll
            for (int nt = 0; nt < 8; nt++) {
                float e = __expf(acc[mt][nt][r] - mx[mt][r]);
                acc[mt][nt][r] = e;
                s += e;
            }
            #pragma unroll
            for (int off = 1; off <= 8; off <<= 1) s += __shfl_xor(s, off);
            sm[mt][r] = s;
        }
    if ((lane & 15) == 0) {
        #pragma unroll
        for (int mt = 0; mt < 2; mt++)
            #pragma unroll
            for (int r = 0; r < 4; r++)
                red[wm + mt * 16 + rsub + r][w >> 1] = sm[mt][r];
    }
    __syncthreads();

    // ---- normalize + store
    #pragma unroll
    for (int mt = 0; mt < 2; mt++)
        #pragma unroll
        for (int r = 0; r < 4; r++) {
            int rl = wm + mt * 16 + rsub + r;
            f32x4 v = *(const f32x4*)(&red[rl][0]);
            float inv = 1.0f / (v[0] + v[1] + v[2] + v[3]);
            float* orow = Out + ((size_t)b * 512 + qbase + rl) * 512 + wn + (lane & 15);
            #pragma unroll
            for (int nt = 0; nt < 8; nt++)
                orow[nt * 16] = acc[mt][nt][r] * inv;
        }
}

// ---------------------------------------------------------------------------
extern "C" void kernel_launch(void* const* d_in, const int* in_sizes, int n_in,
                              void* d_out, int out_size, void* d_ws, size_t ws_size,
                              hipStream_t stream) {
    const float* ar    = (const float*)d_in[0];   // [B,U,AE]
    const float* own   = (const float*)d_in[1];   // [B,U,UE]
    const float* enemy = (const float*)d_in[2];   // [B,U,UE]
    const int*   n_own   = (const int*)d_in[3];   // nr_own_units
    const int*   n_enemy = (const int*)d_in[4];   // nr_units_enemy
    const int*   n_flags = (const int*)d_in[5];   // nr_own_flags
    const float* Wq = (const float*)d_in[6];
    const float* bq = (const float*)d_in[7];
    const float* Wk = (const float*)d_in[8];
    const float* bk = (const float*)d_in[9];
    float* out = (float*)d_out;

    char* ws = (char*)d_ws;
    _Float16* WqT = (_Float16*)(ws);                       // 256x1280 = 655360 B
    _Float16* WkT = (_Float16*)(ws + 655360);              // 256x256  = 131072 B
    _Float16* Qh  = (_Float16*)(ws + 786432);              // [64][8][512][32] f16
    _Float16* Kh  = (_Float16*)(ws + 786432 + 16777216);   // [64][8][512][32] f16

    prep<<<dim3((KQ * A + A * A) / 256), dim3(256), 0, stream>>>(Wq, Wk, WqT, WkT);

    // Q = concat(ar, own) @ Wq + bq   (BM=64 -> grid 512)
    gemm<<<dim3(512), dim3(512), 0, stream>>>(ar, AE, AE, own, UE, WqT, bq, Qh, KQ);
    // K = enemy @ Wk + bk  (split=0 -> always A2 path)
    gemm<<<dim3(512), dim3(512), 0, stream>>>(enemy, UE, 0, enemy, UE, WkT, bk, Kh, A);

    attn<<<dim3(8, B), dim3(512), 0, stream>>>(Qh, Kh, n_own, n_enemy, n_flags, out);
}

// Round 3
// 322.637 us; speedup vs baseline: 1.1377x; 1.0300x over previous
//
#include <hip/hip_runtime.h>

// Problem constants
constexpr int B  = 64;
constexpr int U  = 512;
constexpr int AE = 1024;
constexpr int UE = 256;
constexpr int A  = 256;     // head size
constexpr int KQ = AE + UE; // 1280

typedef _Float16 f16x8 __attribute__((ext_vector_type(8)));
typedef float    f32x4 __attribute__((ext_vector_type(4)));

// Baked position: logical k-chunk j (=c>>3) of row u stored at chunk j^((u>>1)&3).
// This is R0's verified 2-way-free LDS swizzle, moved into the DATA so the
// global->LDS copy can be linear (global_load_lds writes base+lane*16 only).

// ---------------------------------------------------------------------------
// K0: build baked-linear staged-tile weight images:
//   BTq [20][2][256][32] fp16 : [k-tile][k-plane][n-row][baked k-pos]
//   BTk [ 4][2][256][32] fp16
// value at [kp][row][pos] = W[k = kp*32 + ((pos>>3)^((row>>1)&3))*8 + (pos&7)][row]
// Output-coalesced (consecutive threads -> consecutive fp16 writes).
// ---------------------------------------------------------------------------
__global__ void prep(const float* __restrict__ Wq, const float* __restrict__ Wk,
                     _Float16* __restrict__ BTq, _Float16* __restrict__ BTk) {
    int idx = blockIdx.x * 256 + threadIdx.x;
    const float* W;
    _Float16* Dst;
    int rem;
    if (idx < 20 * 2 * 256 * 32) { W = Wq; Dst = BTq; rem = idx; }
    else                         { W = Wk; Dst = BTk; rem = idx - 20 * 2 * 256 * 32; }
    int pos = rem & 31;
    int row = (rem >> 5) & 255;
    int kp  = rem >> 13;               // k-plane index (32 k each)
    int s = pos >> 3, e = pos & 7;
    int c = ((s ^ ((row >> 1) & 3)) << 3) | e;
    int k = kp * 32 + c;
    Dst[rem] = (_Float16)W[(size_t)k * 256 + row];
}

// ---------------------------------------------------------------------------
// K1/K2: C[m][n] = (concat A1|A2)[m][k] * B[k][n] + bias[n], fp16 out in
// permuted+baked layout [bb=row>>9][c5=col>>5][u=row&511][bakedpos(col&31,u)].
//
// R3: B-staging via global_load_lds direct-to-LDS (4x dwordx4 per wave per
// iter, contiguous 32-KB tile stream from baked BT) — removes the VGPR
// round-trip + vmcnt-at-ds_write serialization (guide m97/m193: +67%).
// A stays reg-staged (fp32->fp16 cvt requires VGPRs), R0 swizzle verbatim.
// Double-buffered LDS (80 KB, 2 blocks/CU), one raw barrier per iter.
// ---------------------------------------------------------------------------
__global__ __launch_bounds__(512) void gemm(
    const float* __restrict__ A1, int s1, int split,
    const float* __restrict__ A2, int s2,
    const _Float16* __restrict__ BT,   // baked-linear [nk][2][256][32]
    const float* __restrict__ bias,    // [256]
    _Float16* __restrict__ Out,        // permuted+baked, see above
    int Ktot)
{
    __shared__ __align__(16) _Float16 Al[2][2][64][32];   // [buf][plane][row][32] 16 KB
    __shared__ __align__(16) _Float16 Bl[2][2][256][32];  // [buf][plane][row][32] 64 KB

    const int t    = threadIdx.x;
    const int lane = t & 63;
    const int w    = t >> 6;              // 0..7
    const int mbase = blockIdx.x * 64;

    const int wm = (w & 1) * 32;          // wave row base
    const int wn = (w >> 1) * 64;         // wave col base

    f32x4 acc[2][4] = {};

    // A staging mapping: thread -> (row ar, 8-elem k-chunk aq)  [R0 verbatim]
    const int ar  = t >> 3;               // 0..63
    const int aq  = t & 7;                // 0..7
    const int ap  = aq >> 2;              // plane
    const int asw = ((aq & 3) ^ ((ar >> 1) & 3)) * 8;  // swizzled chunk offset
    const size_t grow = mbase + ar;

    float4 areg0, areg1;

    auto loadA = [&](int k0) {
        int kg = k0 + aq * 8;
        const float* src = (kg < split) ? (A1 + grow * (size_t)s1 + kg)
                                        : (A2 + grow * (size_t)s2 + (kg - split));
        areg0 = ((const float4*)src)[0];
        areg1 = ((const float4*)src)[1];
    };
    // B: contiguous 32-KB tile -> LDS, linear. Per wave: 4 KB (4 x 1 KB instrs).
    auto stageB = [&](int kb, int nb) {
        const char* g = (const char*)BT + (size_t)kb * 32768 + w * 4096 + (lane << 4);
        char* l = (char*)(&Bl[nb][0][0][0]) + w * 4096;
        #pragma unroll
        for (int i = 0; i < 4; i++)
            __builtin_amdgcn_global_load_lds(
                (const __attribute__((address_space(1))) void*)(g + i * 1024),
                (__attribute__((address_space(3))) void*)(l + i * 1024), 16, 0, 0);
    };
    auto writeA = [&](int nb) {
        f16x8 hv;
        hv[0] = (_Float16)areg0.x; hv[1] = (_Float16)areg0.y;
        hv[2] = (_Float16)areg0.z; hv[3] = (_Float16)areg0.w;
        hv[4] = (_Float16)areg1.x; hv[5] = (_Float16)areg1.y;
        hv[6] = (_Float16)areg1.z; hv[7] = (_Float16)areg1.w;
        *(f16x8*)(&Al[nb][ap][ar][asw]) = hv;
    };

    // prologue: stage tile 0 into buf 0
    loadA(0);            // A loads issued first (oldest in vmcnt FIFO)
    stageB(0, 0);        // then B direct-LDS
    writeA(0);           // compiler waits vmcnt for A regs only (counted)
    asm volatile("s_waitcnt vmcnt(0) lgkmcnt(0)" ::: "memory");
    __builtin_amdgcn_s_barrier();
    __builtin_amdgcn_sched_barrier(0);

    const int rsw = (((lane & 15) >> 1) & 3);  // read-side swizzle component
    const int nk = Ktot >> 6;
    int cur = 0;
    for (int kb = 0; kb < nk; kb++) {
        const bool more = (kb + 1 < nk);
        if (more) {
            loadA(kb * 64 + 64);        // A first: waiting on A later keeps B flying
            stageB(kb + 1, cur ^ 1);    // B(t+1) lands during MFMA phase + A-write
        }
        __builtin_amdgcn_sched_barrier(0);   // pin issue phase before compute
        #pragma unroll
        for (int p = 0; p < 2; p++) {
            f16x8 af[2], bf[4];
            #pragma unroll
            for (int mt = 0; mt < 2; mt++)
                af[mt] = *(const f16x8*)(&Al[cur][p][wm + mt * 16 + (lane & 15)][(((lane >> 4) ^ rsw)) * 8]);
            #pragma unroll
            for (int nt = 0; nt < 4; nt++)
                bf[nt] = *(const f16x8*)(&Bl[cur][p][wn + nt * 16 + (lane & 15)][(((lane >> 4) ^ rsw)) * 8]);
            #pragma unroll
            for (int mt = 0; mt < 2; mt++)
                #pragma unroll
                for (int nt = 0; nt < 4; nt++)
                    acc[mt][nt] = __builtin_amdgcn_mfma_f32_16x16x32_f16(
                        af[mt], bf[nt], acc[mt][nt], 0, 0, 0);
        }
        __builtin_amdgcn_sched_barrier(0);   // pin A-write AFTER the MFMA phase
        if (more) writeA(cur ^ 1);           // waits vmcnt(4): A regs ready, B still flying
        asm volatile("s_waitcnt vmcnt(0) lgkmcnt(0)" ::: "memory");  // drain B(t+1)+A write
        __builtin_amdgcn_s_barrier();        // raw barrier
        __builtin_amdgcn_sched_barrier(0);
        cur ^= 1;
    }

    // epilogue: C layout col=lane&15, row=(lane>>4)*4+reg; permuted+baked store
    const int col0 = wn + (lane & 15);
    const int rsub = (lane >> 4) * 4;
    #pragma unroll
    for (int nt = 0; nt < 4; nt++) {
        const int col = col0 + nt * 16;
        const float bv = bias[col];
        const int c5 = col >> 5, c31 = col & 31;
        const int sc = c31 >> 3, ei = c31 & 7;
        #pragma unroll
        for (int mt = 0; mt < 2; mt++)
            #pragma unroll
            for (int r = 0; r < 4; r++) {
                int row = mbase + wm + mt * 16 + rsub + r;
                int bb = row >> 9, u = row & 511;
                int posb = ((sc ^ ((u >> 1) & 3)) << 3) | ei;   // bake attn LDS swizzle
                Out[(((size_t)bb * 8 + c5) * 512 + u) * 32 + posb] =
                    (_Float16)(acc[mt][nt][r] + bv);
            }
    }
}

// ---------------------------------------------------------------------------
// K3: block = (batch, 64 q-rows), 512 thr / 8 waves. S = Qh Kh^T / 16 with
// multiplicative mask, row softmax entirely in registers + tiny LDS combine.
// K streamed in 8 chunks of 32 d via register-prefetch pipeline.
// R3 delta: Qh/Kh arrive pre-swizzled (baked), so LDS writes are LINEAR
// byte-copies; frag-read XORs unchanged. Pipeline untouched.
// ---------------------------------------------------------------------------
__global__ __launch_bounds__(512) void attn(
    const _Float16* __restrict__ Qh, const _Float16* __restrict__ Kh,
    const int* __restrict__ nr_own_units, const int* __restrict__ nr_units_enemy,
    const int* __restrict__ nr_own_flags, float* __restrict__ Out)
{
    __shared__ __align__(16) _Float16 Ql[8][64][32];   // 32 KB, 8 d-chunks
    __shared__ __align__(16) _Float16 Kl[512][32];     // 32 KB, one d-chunk
    __shared__ float red[64][4];                       // per-row cross-wave scratch

    const int t    = threadIdx.x;
    const int lane = t & 63;
    const int w    = t >> 6;                 // 0..7
    const int b    = blockIdx.y;
    const int qbase = blockIdx.x * 64;

    const int nf = nr_own_flags[b];
    const int nu = nr_own_units[b];
    const int ne = nr_units_enemy[b];

    const int wm = (w & 1) * 32;             // wave row base (0/32)
    const int wn = (w >> 1) * 128;           // wave col base (0..384)

    // ---- stage Q (once): linear copy of baked image
    f16x8 qreg[4];
    {
        const _Float16* Qb = Qh + ((size_t)b * 8 * 512 + qbase) * 32;
        #pragma unroll
        for (int j = 0; j < 4; j++) {
            int s = j * 512 + t;
            int p = s >> 8, row = (s & 255) >> 2, cq = s & 3;
            qreg[j] = *(const f16x8*)(Qb + ((size_t)p * 512 + row) * 32 + cq * 8);
        }
        #pragma unroll
        for (int j = 0; j < 4; j++) {
            int s = j * 512 + t;
            int p = s >> 8, row = (s & 255) >> 2, cq = s & 3;
            *(f16x8*)(&Ql[p][row][cq * 8]) = qreg[j];   // linear (swizzle baked)
        }
    }

    // ---- K chunk staging mapping: s = j*512 + t -> row = s>>2, cq = s&3
    const _Float16* Kb = Kh + (size_t)b * 8 * 512 * 32;
    f16x8 kreg[4];
    const int krow = t >> 2;                 // + j*128
    const int kq   = t & 3;
    auto loadK = [&](int c) {
        const _Float16* Kc = Kb + (size_t)c * 512 * 32;
        #pragma unroll
        for (int j = 0; j < 4; j++)
            kreg[j] = *(const f16x8*)(Kc + ((size_t)(j * 128 + krow)) * 32 + kq * 8);
    };
    loadK(0);

    f32x4 acc[2][8] = {};
    const int rsw = (((lane & 15) >> 1) & 3);
    for (int c = 0; c < 8; c++) {
        __syncthreads();   // c==0: publish Ql; else: prev Kl readers done
        #pragma unroll
        for (int j = 0; j < 4; j++) {
            int row = j * 128 + krow;
            *(f16x8*)(&Kl[row][kq * 8]) = kreg[j];      // linear (swizzle baked)
        }
        __syncthreads();
        if (c < 7) loadK(c + 1);
        f16x8 af[2], bf[8];
        #pragma unroll
        for (int mt = 0; mt < 2; mt++)
            af[mt] = *(const f16x8*)(&Ql[c][wm + mt * 16 + (lane & 15)][((lane >> 4) ^ rsw) * 8]);
        #pragma unroll
        for (int nt = 0; nt < 8; nt++)
            bf[nt] = *(const f16x8*)(&Kl[wn + nt * 16 + (lane & 15)][((lane >> 4) ^ rsw) * 8]);
        #pragma unroll
        for (int mt = 0; mt < 2; mt++)
            #pragma unroll
            for (int nt = 0; nt < 8; nt++)
                acc[mt][nt] = __builtin_amdgcn_mfma_f32_16x16x32_f16(
                    af[mt], bf[nt], acc[mt][nt], 0, 0, 0);
    }

    // ---- mask + scale in registers
    const int rsub = (lane >> 4) * 4;
    #pragma unroll
    for (int mt = 0; mt < 2; mt++)
        #pragma unroll
        for (int nt = 0; nt < 8; nt++)
            #pragma unroll
            for (int r = 0; r < 4; r++) {
                int rl = wm + mt * 16 + rsub + r;
                int uq = qbase + rl;
                int col = wn + nt * 16 + (lane & 15);
                bool ok = (col < ne) && (uq >= nf) && (uq < nu);
                acc[mt][nt][r] = acc[mt][nt][r] * 0.0625f * (ok ? 1.0f : 1e-9f);
            }

    // ---- row max: over nt in-lane, then across 16-lane group, then cross-wave
    float mx[2][4];
    #pragma unroll
    for (int mt = 0; mt < 2; mt++)
        #pragma unroll
        for (int r = 0; r < 4; r++) {
            float m = acc[mt][0][r];
            #pragma unroll
            for (int nt = 1; nt < 8; nt++) m = fmaxf(m, acc[mt][nt][r]);
            #pragma unroll
            for (int off = 1; off <= 8; off <<= 1) m = fmaxf(m, __shfl_xor(m, off));
            mx[mt][r] = m;
        }
    if ((lane & 15) == 0) {
        #pragma unroll
        for (int mt = 0; mt < 2; mt++)
            #pragma unroll
            for (int r = 0; r < 4; r++)
                red[wm + mt * 16 + rsub + r][w >> 1] = mx[mt][r];
    }
    __syncthreads();
    #pragma unroll
    for (int mt = 0; mt < 2; mt++)
        #pragma unroll
        for (int r = 0; r < 4; r++) {
            f32x4 v = *(const f32x4*)(&red[wm + mt * 16 + rsub + r][0]);
            mx[mt][r] = fmaxf(fmaxf(v[0], v[1]), fmaxf(v[2], v[3]));
        }
    __syncthreads();   // everyone read max before red is reused for sums

    // ---- exp + row sum
    float sm[2][4];
    #pragma unroll
    for (int mt = 0; mt < 2; mt++)
        #pragma unroll
        for (int r = 0; r < 4; r++) {
            float s = 0.f;
            #pragma unroll
            for (int nt = 0; nt < 8; nt++) {
                float e = __expf(acc[mt][nt][r] - mx[mt][r]);
                acc[mt][nt][r] = e;
                s += e;
            }
            #pragma unroll
            for (int off = 1; off <= 8; off <<= 1) s += __shfl_xor(s, off);
            sm[mt][r] = s;
        }
    if ((lane & 15) == 0) {
        #pragma unroll
        for (int mt = 0; mt < 2; mt++)
            #pragma unroll
            for (int r = 0; r < 4; r++)
                red[wm + mt * 16 + rsub + r][w >> 1] = sm[mt][r];
    }
    __syncthreads();

    // ---- normalize + store
    #pragma unroll
    for (int mt = 0; mt < 2; mt++)
        #pragma unroll
        for (int r = 0; r < 4; r++) {
            int rl = wm + mt * 16 + rsub + r;
            f32x4 v = *(const f32x4*)(&red[rl][0]);
            float inv = 1.0f / (v[0] + v[1] + v[2] + v[3]);
            float* orow = Out + ((size_t)b * 512 + qbase + rl) * 512 + wn + (lane & 15);
            #pragma unroll
            for (int nt = 0; nt < 8; nt++)
                orow[nt * 16] = acc[mt][nt][r] * inv;
        }
}

// ---------------------------------------------------------------------------
extern "C" void kernel_launch(void* const* d_in, const int* in_sizes, int n_in,
                              void* d_out, int out_size, void* d_ws, size_t ws_size,
                              hipStream_t stream) {
    const float* ar    = (const float*)d_in[0];   // [B,U,AE]
    const float* own   = (const float*)d_in[1];   // [B,U,UE]
    const float* enemy = (const float*)d_in[2];   // [B,U,UE]
    const int*   n_own   = (const int*)d_in[3];   // nr_own_units
    const int*   n_enemy = (const int*)d_in[4];   // nr_units_enemy
    const int*   n_flags = (const int*)d_in[5];   // nr_own_flags
    const float* Wq = (const float*)d_in[6];
    const float* bq = (const float*)d_in[7];
    const float* Wk = (const float*)d_in[8];
    const float* bk = (const float*)d_in[9];
    float* out = (float*)d_out;

    char* ws = (char*)d_ws;
    _Float16* BTq = (_Float16*)(ws);                       // 20*32768 = 655360 B
    _Float16* BTk = (_Float16*)(ws + 655360);              // 4*32768  = 131072 B
    _Float16* Qh  = (_Float16*)(ws + 786432);              // [64][8][512][32] f16
    _Float16* Kh  = (_Float16*)(ws + 786432 + 16777216);   // [64][8][512][32] f16

    // 24 k-tiles total (Q:20, K:4) * 2*256*32 elems = 393216 -> 1536 blocks
    prep<<<dim3(1536), dim3(256), 0, stream>>>(Wq, Wk, BTq, BTk);

    // Q = concat(ar, own) @ Wq + bq   (BM=64 -> grid 512)
    gemm<<<dim3(512), dim3(512), 0, stream>>>(ar, AE, AE, own, UE, BTq, bq, Qh, KQ);
    // K = enemy @ Wk + bk  (split=0 -> always A2 path)
    gemm<<<dim3(512), dim3(512), 0, stream>>>(enemy, UE, 0, enemy, UE, BTk, bk, Kh, A);

    attn<<<dim3(8, B), dim3(512), 0, stream>>>(Qh, Kh, n_own, n_enemy, n_flags, out);
}